// Round 1
// baseline (244.034 us; speedup 1.0000x reference)
//
#include <hip/hip_runtime.h>
#include <hip/hip_bf16.h>

// Attention with relative position bias: B=1, L=4096, D=512, H=8, HD=64
// bias[h,i,j] = rel[h, j-i+4095]

typedef __attribute__((ext_vector_type(8))) short bf16x8;
typedef __attribute__((ext_vector_type(4))) float f32x4;

__device__ __forceinline__ short f2bf(float f) {
    unsigned u = __builtin_bit_cast(unsigned, f);
    u += 0x7fff + ((u >> 16) & 1);
    return (short)(u >> 16);
}

// ---------------- prep kernels ----------------
__global__ __launch_bounds__(256) void k_prep_xp(const float* __restrict__ x,
                                                 const float* __restrict__ pos,
                                                 short* __restrict__ xp) {
    int i = (blockIdx.x * 256 + threadIdx.x) * 8;
    float4 a0 = *(const float4*)(x + i);
    float4 a1 = *(const float4*)(x + i + 4);
    float4 b0 = *(const float4*)(pos + i);
    float4 b1 = *(const float4*)(pos + i + 4);
    bf16x8 v;
    v[0] = f2bf(a0.x + b0.x); v[1] = f2bf(a0.y + b0.y);
    v[2] = f2bf(a0.z + b0.z); v[3] = f2bf(a0.w + b0.w);
    v[4] = f2bf(a1.x + b1.x); v[5] = f2bf(a1.y + b1.y);
    v[6] = f2bf(a1.z + b1.z); v[7] = f2bf(a1.w + b1.w);
    *(bf16x8*)(xp + i) = v;
}

// WqkvT[n][k] = W*[k][n'] (bf16), n in [0,1536), k in [0,512). Wq scaled by 1/8.
__global__ __launch_bounds__(256) void k_prep_wqkv(const float* __restrict__ Wq,
                                                   const float* __restrict__ Wk,
                                                   const float* __restrict__ Wv,
                                                   short* __restrict__ WT) {
    int idx = blockIdx.x * 256 + threadIdx.x;   // 1536*512
    int n = idx >> 9, k = idx & 511;
    int nn = n & 511;
    const float* src = (n < 512) ? Wq : (n < 1024 ? Wk : Wv);
    float scale = (n < 512) ? 0.125f : 1.0f;
    WT[idx] = f2bf(src[k * 512 + nn] * scale);
}

__global__ __launch_bounds__(256) void k_prep_wo(const float* __restrict__ Wo,
                                                 short* __restrict__ WoT) {
    int idx = blockIdx.x * 256 + threadIdx.x;   // 512*512
    int n = idx >> 9, k = idx & 511;
    WoT[idx] = f2bf(Wo[k * 512 + n]);
}

// ---------------- GEMM: C[M x N] = A[M x 512] * Bt[N x 512]^T ----------------
// MODE 0: QKV projection -> write Q/K/V bf16 in [h][l][hd] layout, add biases
// MODE 1: out projection -> write f32 d_out + bo
template <int MODE>
__global__ __launch_bounds__(256) void k_gemm(const short* __restrict__ A,
                                              const short* __restrict__ Bt,
                                              const float* __restrict__ bias0,
                                              const float* __restrict__ bias1,
                                              const float* __restrict__ bias2,
                                              short* __restrict__ Qg,
                                              short* __restrict__ Kg,
                                              short* __restrict__ Vg,
                                              float* __restrict__ Cout) {
    __shared__ short Al[128][72];
    __shared__ short Bl[128][72];
    const int tid = threadIdx.x;
    const int lane = tid & 63, wid = tid >> 6;
    const int wm = wid >> 1, wn = wid & 1;
    const int mb = blockIdx.y * 128, nb = blockIdx.x * 128;
    const int lr = lane & 15, lg = lane >> 4;

    f32x4 acc[4][4] = {};

    for (int kk = 0; kk < 512; kk += 64) {
        #pragma unroll
        for (int i = 0; i < 4; ++i) {
            int o = tid + 256 * i;          // 1024 octets per tile
            int row = o >> 3, c8 = (o & 7) * 8;
            *(uint4*)(&Al[row][c8]) = *(const uint4*)(A + (size_t)(mb + row) * 512 + kk + c8);
            *(uint4*)(&Bl[row][c8]) = *(const uint4*)(Bt + (size_t)(nb + row) * 512 + kk + c8);
        }
        __syncthreads();
        #pragma unroll
        for (int ks = 0; ks < 2; ++ks) {
            bf16x8 af[4], bfr[4];
            #pragma unroll
            for (int t = 0; t < 4; ++t) {
                af[t]  = *(const bf16x8*)(&Al[wm * 64 + t * 16 + lr][ks * 32 + lg * 8]);
                bfr[t] = *(const bf16x8*)(&Bl[wn * 64 + t * 16 + lr][ks * 32 + lg * 8]);
            }
            #pragma unroll
            for (int mt = 0; mt < 4; ++mt)
                #pragma unroll
                for (int nt = 0; nt < 4; ++nt)
                    acc[mt][nt] = __builtin_amdgcn_mfma_f32_16x16x32_bf16(
                        af[mt], bfr[nt], acc[mt][nt], 0, 0, 0);
        }
        __syncthreads();
    }

    #pragma unroll
    for (int mt = 0; mt < 4; ++mt) {
        #pragma unroll
        for (int nt = 0; nt < 4; ++nt) {
            #pragma unroll
            for (int r = 0; r < 4; ++r) {
                int m = mb + wm * 64 + mt * 16 + lg * 4 + r;
                int n = nb + wn * 64 + nt * 16 + lr;
                float v = acc[mt][nt][r];
                if (MODE == 0) {
                    int which = n >> 9;
                    int nn = n & 511;
                    int h = nn >> 6, hd = nn & 63;
                    const float* bp = (which == 0) ? bias0 : (which == 1 ? bias1 : bias2);
                    v += bp[nn] * (which == 0 ? 0.125f : 1.0f);
                    short* dst = (which == 0) ? Qg : (which == 1 ? Kg : Vg);
                    dst[((size_t)h * 4096 + m) * 64 + hd] = f2bf(v);
                } else {
                    Cout[(size_t)m * 512 + n] = v + bias0[n];
                }
            }
        }
    }
}

// ---------------- flash attention ----------------
// grid (L/64, H); 4 waves, wave w owns q rows [qb + 16w, qb + 16w + 16)
__global__ __launch_bounds__(256) void k_attn(const short* __restrict__ Qg,
                                              const short* __restrict__ Kg,
                                              const short* __restrict__ Vg,
                                              const float* __restrict__ rel,
                                              short* __restrict__ AO) {
    __shared__ short Kl[64][72];
    __shared__ short Vt[64][72];   // transposed: rows = d, cols = k
    __shared__ short Pl[4][16][72];
    __shared__ float biasl[128];

    const int tid = threadIdx.x;
    const int lane = tid & 63, wq = tid >> 6;
    const int lr = lane & 15, lg = lane >> 4;
    const int h = blockIdx.y;
    const int qb = blockIdx.x * 64;

    const short* Qh = Qg + (size_t)h * 4096 * 64;
    const short* Kh = Kg + (size_t)h * 4096 * 64;
    const short* Vh = Vg + (size_t)h * 4096 * 64;
    const float* relh = rel + h * 8192;

    bf16x8 qf[2];
    #pragma unroll
    for (int dk = 0; dk < 2; ++dk)
        qf[dk] = *(const bf16x8*)(Qh + (size_t)(qb + wq * 16 + lr) * 64 + dk * 32 + lg * 8);

    f32x4 acc[4] = {};
    float m[4], l[4];
    #pragma unroll
    for (int r = 0; r < 4; ++r) { m[r] = -1e30f; l[r] = 0.0f; }

    const float L2E = 1.4426950408889634f;

    for (int kb = 0; kb < 4096; kb += 64) {
        // stage K (row-major) and V (transposed)
        #pragma unroll
        for (int i = 0; i < 2; ++i) {
            int o = tid + 256 * i;          // 512 octets
            int row = o >> 3, c8 = (o & 7) * 8;
            *(uint4*)(&Kl[row][c8]) = *(const uint4*)(Kh + (size_t)(kb + row) * 64 + c8);
            bf16x8 vv = *(const bf16x8*)(Vh + (size_t)(kb + row) * 64 + c8);
            #pragma unroll
            for (int j = 0; j < 8; ++j) Vt[c8 + j][row] = vv[j];
        }
        // bias sliding window: rel[h, (kb - qb + 4032) + i], i in [0,128)
        if (tid < 128) biasl[tid] = relh[4032 + kb - qb + tid];
        __syncthreads();

        // S = Q @ K^T  (per wave: 16 q x 64 k)
        f32x4 s[4] = {};
        #pragma unroll
        for (int dk = 0; dk < 2; ++dk) {
            #pragma unroll
            for (int t = 0; t < 4; ++t) {
                bf16x8 kf = *(const bf16x8*)(&Kl[t * 16 + lr][dk * 32 + lg * 8]);
                s[t] = __builtin_amdgcn_mfma_f32_16x16x32_bf16(qf[dk], kf, s[t], 0, 0, 0);
            }
        }
        // + bias: element (q=lg*4+r, k=16t+lr)
        int bbase = 63 + lr - wq * 16 - lg * 4;
        #pragma unroll
        for (int t = 0; t < 4; ++t)
            #pragma unroll
            for (int r = 0; r < 4; ++r)
                s[t][r] += biasl[bbase + 16 * t - r];

        // online softmax (rows live in reg slot r within 16-lane group lg)
        float mx[4];
        #pragma unroll
        for (int r = 0; r < 4; ++r)
            mx[r] = fmaxf(fmaxf(s[0][r], s[1][r]), fmaxf(s[2][r], s[3][r]));
        #pragma unroll
        for (int off = 1; off < 16; off <<= 1)
            #pragma unroll
            for (int r = 0; r < 4; ++r)
                mx[r] = fmaxf(mx[r], __shfl_xor(mx[r], off));

        float sc[4], rs[4];
        #pragma unroll
        for (int r = 0; r < 4; ++r) {
            float mn = fmaxf(m[r], mx[r]);
            sc[r] = exp2f((m[r] - mn) * L2E);
            m[r] = mn;
            rs[r] = 0.0f;
        }
        #pragma unroll
        for (int t = 0; t < 4; ++t)
            #pragma unroll
            for (int r = 0; r < 4; ++r) {
                float p = exp2f((s[t][r] - m[r]) * L2E);
                s[t][r] = p;
                rs[r] += p;
            }
        #pragma unroll
        for (int off = 1; off < 16; off <<= 1)
            #pragma unroll
            for (int r = 0; r < 4; ++r)
                rs[r] += __shfl_xor(rs[r], off);
        #pragma unroll
        for (int r = 0; r < 4; ++r)
            l[r] = l[r] * sc[r] + rs[r];

        // rescale O, stash P (bf16) to per-wave LDS
        #pragma unroll
        for (int dt = 0; dt < 4; ++dt)
            #pragma unroll
            for (int r = 0; r < 4; ++r)
                acc[dt][r] *= sc[r];
        #pragma unroll
        for (int t = 0; t < 4; ++t)
            #pragma unroll
            for (int r = 0; r < 4; ++r)
                Pl[wq][lg * 4 + r][lr + 16 * t] = f2bf(s[t][r]);

        // O += P @ V
        #pragma unroll
        for (int ks = 0; ks < 2; ++ks) {
            bf16x8 pa = *(const bf16x8*)(&Pl[wq][lr][ks * 32 + lg * 8]);
            #pragma unroll
            for (int dt = 0; dt < 4; ++dt) {
                bf16x8 vb = *(const bf16x8*)(&Vt[dt * 16 + lr][ks * 32 + lg * 8]);
                acc[dt] = __builtin_amdgcn_mfma_f32_16x16x32_bf16(pa, vb, acc[dt], 0, 0, 0);
            }
        }
        __syncthreads();
    }

    // normalize + write attn_out (bf16, [l][h*64+hd])
    #pragma unroll
    for (int dt = 0; dt < 4; ++dt)
        #pragma unroll
        for (int r = 0; r < 4; ++r) {
            int qg = qb + wq * 16 + lg * 4 + r;
            float v = acc[dt][r] / l[r];
            AO[(size_t)qg * 512 + h * 64 + dt * 16 + lr] = f2bf(v);
        }
}

// ---------------- launch ----------------
extern "C" void kernel_launch(void* const* d_in, const int* in_sizes, int n_in,
                              void* d_out, int out_size, void* d_ws, size_t ws_size,
                              hipStream_t stream) {
    const float* x   = (const float*)d_in[0];
    const float* pos = (const float*)d_in[1];
    const float* rel = (const float*)d_in[2];
    const float* Wq  = (const float*)d_in[3];
    const float* bq  = (const float*)d_in[4];
    const float* Wk  = (const float*)d_in[5];
    const float* bk  = (const float*)d_in[6];
    const float* Wv  = (const float*)d_in[7];
    const float* bv  = (const float*)d_in[8];
    const float* Wo  = (const float*)d_in[9];
    const float* bo  = (const float*)d_in[10];
    float* out = (float*)d_out;

    char* ws = (char*)d_ws;
    short* xp    = (short*)ws;  ws += (size_t)4096 * 512 * 2;   // also reused as AO
    short* WqkvT = (short*)ws;  ws += (size_t)1536 * 512 * 2;
    short* WoT   = (short*)ws;  ws += (size_t)512 * 512 * 2;
    short* Qg    = (short*)ws;  ws += (size_t)8 * 4096 * 64 * 2;
    short* Kg    = (short*)ws;  ws += (size_t)8 * 4096 * 64 * 2;
    short* Vg    = (short*)ws;  ws += (size_t)8 * 4096 * 64 * 2;
    short* AO    = (short*)ws;  ws += (size_t)4096 * 512 * 2;

    k_prep_xp<<<dim3(4096 * 512 / (256 * 8)), 256, 0, stream>>>(x, pos, xp);
    k_prep_wqkv<<<dim3(1536 * 512 / 256), 256, 0, stream>>>(Wq, Wk, Wv, WqkvT);
    k_prep_wo<<<dim3(512 * 512 / 256), 256, 0, stream>>>(Wo, WoT);

    k_gemm<0><<<dim3(12, 32), 256, 0, stream>>>(xp, WqkvT, bq, bk, bv, Qg, Kg, Vg, nullptr);
    k_attn<<<dim3(64, 8), 256, 0, stream>>>(Qg, Kg, Vg, rel, AO);
    k_gemm<1><<<dim3(4, 32), 256, 0, stream>>>(AO, WoT, bo, nullptr, nullptr,
                                               nullptr, nullptr, nullptr, out);
}